// Round 3
// baseline (56296.558 us; speedup 1.0000x reference)
//
#include <hip/hip_runtime.h>

// ---------------------------------------------------------------------------
// StackedLstm: 2-layer highway LSTM, B=64, T=512, D=H=1024 (bf16 I/O)
// Recurrence sync: tagged-h dataflow + monotonic arrival counters.
// h value+step packed in one dword, exchanged via agent-scope atomics (LLC).
// R3: sum-gate arrival counters decouple waiting from data re-reads.
//     Producers release-add per-wave after publishing; consumers spin on 4
//     counter dwords then read h ONCE. Tags remain the correctness floor
//     (per-chunk R0-style spin as never-taken fallback).
// ---------------------------------------------------------------------------

#define DEVINL __device__ __forceinline__

typedef short short8v __attribute__((ext_vector_type(8)));
typedef short short4v __attribute__((ext_vector_type(4)));
typedef float f32x4 __attribute__((ext_vector_type(4)));
typedef unsigned int u32x4 __attribute__((ext_vector_type(4)));

#define Bsz   64
#define Tlen  512
#define Hdim  1024
#define NH5   5120
#define NH6   6144
#define TCH   64          // time-chunk length
#define NCH   8           // chunks per layer
#define XELT  33554432    // B*T*H elements

// d_out element offsets: y1 [B,T,H] | final_h [2,B,H] | final_c [2,B,H]
#define OUT_FH 33554432
#define OUT_FC 33685504

// workspace byte offsets (total ~233.1 MB)
#define WS_XBF    0ULL
#define WS_Y0     67108864ULL
#define WS_WIT0   134217728ULL
#define WS_WIT1   146800640ULL
#define WS_WST0   159383552ULL
#define WS_WST1   169869312ULL
#define WS_PI     180355072ULL
#define WS_HW0    230686720ULL   // 4 slots x 64 x 1024 dwords = 1 MB
#define WS_HW1    231735296ULL   // 1 MB
#define WS_CB     232783872ULL   // 256 KB fp32 c-state
#define WS_DFLAG  233046016ULL
#define WS_CNT    233047040ULL   // 2 layers x 2 grps x 4 lines x 64 B = 1 KB

DEVINL short f2bf(float f) {
  unsigned int u = __builtin_bit_cast(unsigned int, f);
  u += 0x7fffu + ((u >> 16) & 1u);          // round-to-nearest-even
  return (short)(u >> 16);
}
DEVINL float bf2f(short s) {
  unsigned int u = ((unsigned int)(unsigned short)s) << 16;
  return __builtin_bit_cast(float, u);
}
DEVINL float fexp2(float x) { return __builtin_amdgcn_exp2f(x); }
DEVINL float frcp(float x)  { return __builtin_amdgcn_rcpf(x); }
DEVINL float sigm(float x)  { return frcp(1.0f + fexp2(-1.44269504f * x)); }
DEVINL float tanh_(float x) { return 1.0f - 2.0f * frcp(1.0f + fexp2(2.88539008f * x)); }

DEVINL void gld_lds16(const short* g, short* lds) {
  __builtin_amdgcn_global_load_lds(
      (const __attribute__((address_space(1))) void*)g,
      (__attribute__((address_space(3))) void*)lds, 16, 0, 0);
}

DEVINL unsigned long long ald64(const unsigned long long* p) {
  return __hip_atomic_load(p, __ATOMIC_RELAXED, __HIP_MEMORY_SCOPE_AGENT);
}
DEVINL unsigned int ald32(const unsigned int* p) {
  return __hip_atomic_load(p, __ATOMIC_RELAXED, __HIP_MEMORY_SCOPE_AGENT);
}
DEVINL void ast32(unsigned int* p, unsigned int v) {
  __hip_atomic_store(p, v, __ATOMIC_RELAXED, __HIP_MEMORY_SCOPE_AGENT);
}

// all 16 tags (8 qwords, 2 dwords each) equal `want` iff AND and OR of the
// tag fields both equal it
DEVINL bool tags_ok(unsigned long long q0, unsigned long long q1,
                    unsigned long long q2, unsigned long long q3,
                    unsigned long long q4, unsigned long long q5,
                    unsigned long long q6, unsigned long long q7,
                    unsigned int want) {
  unsigned long long m = q0 & q1 & q2 & q3 & q4 & q5 & q6 & q7;
  unsigned long long x = q0 | q1 | q2 | q3 | q4 | q5 | q6 | q7;
  return ((unsigned)(m & 0xFFFFu) == want) &
         ((unsigned)((m >> 32) & 0xFFFFu) == want) &
         ((unsigned)(x & 0xFFFFu) == want) &
         ((unsigned)((x >> 32) & 0xFFFFu) == want);
}

// pick hi16 of each dword of q: {lo.hi16, hi.hi16} packed into one dword
DEVINL unsigned int hi16pair(unsigned long long q) {
  return __builtin_amdgcn_perm((unsigned int)(q >> 32), (unsigned int)q,
                               0x07060302u);
}

// ---------------------------------------------------------------------------
// Detect input dtype (bf16 never has exp==0xFF in N(0,1) data) -> dflag.
__global__ void k_detect(const short* __restrict__ x, int* dflag) {
  __shared__ int found;
  if (threadIdx.x == 0) found = 0;
  __syncthreads();
  int hit = 0;
  for (int i = threadIdx.x; i < 16384; i += 256) {
    unsigned int u = (unsigned short)x[i];
    if ((u & 0x7F80u) == 0x7F80u) hit = 1;
  }
  if (hit) atomicOr(&found, 1);
  __syncthreads();
  if (threadIdx.x == 0) *dflag = found;
}

// Zero both tagged-h rings (tags -> 0, h -> +0.0) and arrival counters.
__global__ void k_init(unsigned int* hw0, unsigned int* hw1, unsigned int* cnt) {
  const int i = (blockIdx.x * 256 + threadIdx.x) * 4;
#pragma unroll
  for (int j = 0; j < 4; ++j) { ast32(hw0 + i + j, 0u); ast32(hw1 + i + j, 0u); }
  if (blockIdx.x == 0) ast32(cnt + threadIdx.x, 0u);
}

// x -> bf16 copy (converting from fp32 if detected)
__global__ void k_convert(const void* __restrict__ xin, short* __restrict__ xbf,
                          const int* __restrict__ dflag) {
  const int f32 = *dflag;
  const size_t stride = (size_t)gridDim.x * 1024;
  size_t i = ((size_t)blockIdx.x * 256 + threadIdx.x) * 4;
  for (; i < (size_t)XELT; i += stride) {
    short4v v;
    if (f32) {
      const float4 f = *(const float4*)&((const float*)xin)[i];
      v[0] = f2bf(f.x); v[1] = f2bf(f.y); v[2] = f2bf(f.z); v[3] = f2bf(f.w);
    } else {
      v = *(const short4v*)&((const short*)xin)[i];
    }
    *(short4v*)&xbf[i] = v;
  }
}

// (R,C) -> (C,R) bf16 output, dtype-flagged input, 64x64 tiles
__global__ void k_transpose(const void* __restrict__ in, short* __restrict__ out,
                            int R, int C, const int* __restrict__ dflag) {
  __shared__ short tile[64][65];
  const int f32 = *dflag;
  const int r0 = blockIdx.x << 6, c0 = blockIdx.y << 6;
  const int tid = threadIdx.x;
#pragma unroll
  for (int it = 0; it < 8; ++it) {
    int idx = (it << 8) + tid;
    int r = idx >> 5, c2 = (idx & 31) << 1;
    if (f32) {
      const float* inF = (const float*)in;
      tile[r][c2]     = f2bf(inF[(size_t)(r0 + r) * C + c0 + c2]);
      tile[r][c2 + 1] = f2bf(inF[(size_t)(r0 + r) * C + c0 + c2 + 1]);
    } else {
      int v = *(const int*)&((const short*)in)[(size_t)(r0 + r) * C + c0 + c2];
      tile[r][c2]     = (short)(v & 0xffff);
      tile[r][c2 + 1] = (short)(((unsigned)v) >> 16);
    }
  }
  __syncthreads();
#pragma unroll
  for (int it = 0; it < 8; ++it) {
    int idx = (it << 8) + tid;
    int rr = idx >> 5, k2 = (idx & 31) << 1;
    unsigned int lo = (unsigned short)tile[k2][rr];
    unsigned int hi = (unsigned short)tile[k2 + 1][rr];
    *(unsigned int*)&out[(size_t)(c0 + rr) * R + r0 + k2] = lo | (hi << 16);
  }
}

// ---------------------------------------------------------------------------
// pi_chunk[r, 0:6144] = A[row(r), :] @ Bt^T, rows map the chunk's (b, t0+tt).
__launch_bounds__(256)
__global__ void k_gemm(const short* __restrict__ A, const short* __restrict__ Bt,
                       short* __restrict__ Cmat, int t0) {
  __shared__ short ldsA[128 * 64];
  __shared__ short ldsB[128 * 64];
  const int tid = threadIdx.x, lane = tid & 63, wv = tid >> 6;
  const int wm = wv >> 1, wn = wv & 1;
  const int r0 = blockIdx.x * 128;
  const size_t brow0 = (size_t)blockIdx.y * 128;
  f32x4 acc[4][4] = {};

  for (int kk = 0; kk < Hdim; kk += 64) {
#pragma unroll
    for (int p = 0; p < 4; ++p) {
      int slot = ((wv * 4 + p) << 6) + lane;
      int m = slot >> 3, gp = slot & 7;
      int gl = gp ^ (m & 7);
      int r = r0 + m;
      size_t arow = ((size_t)(r >> 6) * Tlen + t0 + (r & 63)) * Hdim;
      gld_lds16(A + arow + kk + (gl << 3), &ldsA[(wv * 4 + p) << 9]);
      gld_lds16(Bt + (brow0 + m) * Hdim + kk + (gl << 3), &ldsB[(wv * 4 + p) << 9]);
    }
    __syncthreads();
#pragma unroll
    for (int kh = 0; kh < 2; ++kh) {
      short8v af[4], bfv[4];
      const int gl = (kh << 2) + (lane >> 4);
#pragma unroll
      for (int mt = 0; mt < 4; ++mt) {
        int m = wm * 64 + mt * 16 + (lane & 15);
        af[mt] = *(const short8v*)&ldsA[m * 64 + ((gl ^ (m & 7)) << 3)];
      }
#pragma unroll
      for (int nt = 0; nt < 4; ++nt) {
        int n = wn * 64 + nt * 16 + (lane & 15);
        bfv[nt] = *(const short8v*)&ldsB[n * 64 + ((gl ^ (n & 7)) << 3)];
      }
#pragma unroll
      for (int mt = 0; mt < 4; ++mt)
#pragma unroll
        for (int nt = 0; nt < 4; ++nt)
          acc[mt][nt] = __builtin_amdgcn_mfma_f32_16x16x32_bf16(af[mt], bfv[nt], acc[mt][nt], 0, 0, 0);
    }
    __syncthreads();
  }
#pragma unroll
  for (int mt = 0; mt < 4; ++mt)
#pragma unroll
    for (int nt = 0; nt < 4; ++nt)
#pragma unroll
      for (int q = 0; q < 4; ++q) {
        size_t row = (size_t)r0 + wm * 64 + mt * 16 + ((lane >> 4) << 2) + q;
        size_t col = brow0 + wn * 64 + nt * 16 + (lane & 15);
        Cmat[row * NH6 + col] = f2bf(acc[mt][nt][q]);
      }
}

// ---------------------------------------------------------------------------
// Persistent recurrent scan, one TCH-step chunk. 256 WGs x 256 threads.
// WG (grp, gbid): batch rows grp*32..+31, hidden units gbid*8..+7.
// h ring: hw[4][64][1024] dwords, dword = (bf16 h << 16) | ((t+1) & 0xFFFF).
// cnt: per-(grp, wave-slot) monotonic arrival lines (64 B apart). A wave's
// lane 0 release-adds +1 after the wave publishes its 8 rows of h(t).
// Consumers spin until all 4 lines >= 128*t  =>  all WGs completed t-1.
__launch_bounds__(256, 1)
__global__ void k_scan(const short* __restrict__ pi, const short* __restrict__ WsT,
                       const void* __restrict__ bs, void* __restrict__ ybase, int yext,
                       void* __restrict__ outb, int fhoff, int fcoff,
                       unsigned int* hw, unsigned int* cnt, float* cbuf,
                       int t0, int isfirst,
                       const int* __restrict__ lengths, const int* __restrict__ dflag) {
  extern __shared__ short smem[];
  short* Wt = smem;                                   // 48*1032 shorts
  float* psred = (float*)(smem + 48 * 1032);          // 2 x 24*256 floats

  const int tid  = threadIdx.x, lane = tid & 63, wv = tid >> 6;
  const int bid  = blockIdx.x, grp = bid >> 7, gbid = bid & 127;
  const int rb0  = grp * 32;
  const int u0   = gbid * 8;
  const int f32io = *dflag;
  const int yf32  = yext & f32io;

  // --- one-time: weight slice to LDS (cols packed n = gate*8 + unit)
  for (int n = 0; n < 40; ++n) {
    const short* src = WsT + (size_t)((n >> 3) * Hdim + u0 + (n & 7)) * Hdim;
    *(short4v*)&Wt[n * 1032 + tid * 4] = *(const short4v*)&src[tid * 4];
  }
  short4v zz = {0, 0, 0, 0};
  for (int n = 40; n < 48; ++n) *(short4v*)&Wt[n * 1032 + tid * 4] = zz;

  const int grow = tid >> 3, gunit = tid & 7;
  const int gb = rb0 + grow;
  const int mylen = lengths[gb];
  const unsigned int selfoff = ((unsigned)gb << 10) | (unsigned)(u0 + gunit);
  const unsigned int* cline = cnt + (grp << 6);       // 4 lines, 16 dwords apart
  unsigned int* myline = cnt + (grp << 6) + (wv << 4);

  float bias[5];
  int   psoff[5];
#pragma unroll
  for (int g = 0; g < 5; ++g) {
    bias[g] = f32io ? ((const float*)bs)[g * Hdim + u0 + gunit]
                    : bf2f(((const short*)bs)[g * Hdim + u0 + gunit]);
    int n = g * 8 + gunit, nt = n >> 4, cl = n & 15;
    int mt = grow >> 4, rw = grow & 15;
    int ln = ((rw >> 2) << 4) | cl, reg = rw & 3;
    psoff[g] = ((mt * 3 + nt) << 8) + (ln << 2) + reg;
  }

  // restore own state: h from ring slot (t0-1)&3 (zeros if first), c from cbuf
  float h_state = bf2f((short)(ald32(hw + (((unsigned)(t0 + 3) & 3) << 16) + selfoff) >> 16));
  float c_state = isfirst ? 0.0f : cbuf[(size_t)gb * Hdim + u0 + gunit];

  const int kb = wv << 8;                 // wave's K base (dword index)
  const int klane = (lane >> 4) << 3;

  for (int t = t0; t < t0 + TCH; ++t) {
    // pi loads first (independent of h; HBM latency hides under the wait)
    const short* pib = pi + (size_t)(gb * TCH + (t - t0)) * NH6 + u0 + gunit;
    float piv[6];
#pragma unroll
    for (int g = 0; g < 6; ++g) piv[g] = bf2f(pib[g << 10]);

    // --- sum-gate: wait until every WG of this grp completed step t-1.
    const unsigned int need = 128u * (unsigned)t;
    if (need) {
      for (;;) {
        unsigned int c0v = ald32(cline);
        unsigned int c1v = ald32(cline + 16);
        unsigned int c2v = ald32(cline + 32);
        unsigned int c3v = ald32(cline + 48);
        if (c0v >= need && c1v >= need && c2v >= need && c3v >= need) break;
      }
      __threadfence();
    }

    const unsigned long long* hs =
        (const unsigned long long*)hw + ((size_t)((t + 3) & 3) << 15);
    const unsigned int want = (unsigned)(t & 0xFFFF);
    // per-lane qword base: row (rb0 + lane&15), k = kb + klane
    const unsigned long long* pb =
        hs + (((size_t)(rb0 + (lane & 15))) << 9) + ((kb + klane) >> 1);

    // --- recurrent GEMM: load h once (gate guarantees freshness); tags are
    // the correctness floor (fallback spin should never be taken).
    f32x4 acc[2][3] = {};
#pragma unroll
    for (int ks = 0; ks < 8; ++ks) {
      const unsigned long long* p0 = pb + ks * 16;
      unsigned long long q0, q1, q2, q3, q4, q5, q6, q7;
      q0 = ald64(p0);     q1 = ald64(p0 + 1); q2 = ald64(p0 + 2); q3 = ald64(p0 + 3);
      q4 = ald64(p0 + (16 << 9));     q5 = ald64(p0 + (16 << 9) + 1);
      q6 = ald64(p0 + (16 << 9) + 2); q7 = ald64(p0 + (16 << 9) + 3);
      bool ok = tags_ok(q0, q1, q2, q3, q4, q5, q6, q7, want);
      while (!ok) {
        q0 = ald64(p0);     q1 = ald64(p0 + 1); q2 = ald64(p0 + 2); q3 = ald64(p0 + 3);
        q4 = ald64(p0 + (16 << 9));     q5 = ald64(p0 + (16 << 9) + 1);
        q6 = ald64(p0 + (16 << 9) + 2); q7 = ald64(p0 + (16 << 9) + 3);
        ok = tags_ok(q0, q1, q2, q3, q4, q5, q6, q7, want);
      }
      u32x4 ua, ub;
      ua[0] = hi16pair(q0); ua[1] = hi16pair(q1); ua[2] = hi16pair(q2); ua[3] = hi16pair(q3);
      ub[0] = hi16pair(q4); ub[1] = hi16pair(q5); ub[2] = hi16pair(q6); ub[3] = hi16pair(q7);
      short8v a0 = __builtin_bit_cast(short8v, ua);
      short8v a1 = __builtin_bit_cast(short8v, ub);
      const int k = kb + (ks << 5) + klane;
#pragma unroll
      for (int nt = 0; nt < 3; ++nt) {
        short8v bfv = *(const short8v*)&Wt[(nt * 16 + (lane & 15)) * 1032 + k];
        acc[0][nt] = __builtin_amdgcn_mfma_f32_16x16x32_bf16(a0, bfv, acc[0][nt], 0, 0, 0);
        acc[1][nt] = __builtin_amdgcn_mfma_f32_16x16x32_bf16(a1, bfv, acc[1][nt], 0, 0, 0);
      }
    }

    // psred double-buffered by (t&1): no trailing barrier needed.
    float* ps_w = psred + ((t & 1) * 6144);
#pragma unroll
    for (int mt = 0; mt < 2; ++mt)
#pragma unroll
      for (int nt = 0; nt < 3; ++nt)
        *(f32x4*)&ps_w[((wv * 6 + mt * 3 + nt) << 8) + (lane << 2)] = acc[mt][nt];
    __syncthreads();

    float ps[5];
#pragma unroll
    for (int g = 0; g < 5; ++g) {
      int o = psoff[g];
      ps[g] = bias[g] + ps_w[o] + ps_w[1536 + o] + ps_w[3072 + o] + ps_w[4608 + o];
    }
    float ig = sigm(piv[0] + ps[0]);
    float fg = sigm(piv[1] + ps[1]);
    float mg = tanh_(piv[2] + ps[2]);
    float og = sigm(piv[3] + ps[3]);
    float hw_g = sigm(piv[4] + ps[4]);
    float cn  = ig * mg + fg * c_state;
    float outv = og * tanh_(cn);
    outv = hw_g * outv + (1.0f - hw_g) * piv[5];
    const bool valid = (t < mylen);
    if (valid) { c_state = cn; h_state = outv; }

    // publish h(t) tagged t+1 into ring slot t&3 (atomic dword: tag+data
    // together), then the wave's arrival (release covers the wave's stores),
    // then the y-store (kept after the add so its ack isn't on the add path).
    unsigned int pk = (((unsigned)(unsigned short)f2bf(h_state)) << 16) |
                      ((unsigned)((t + 1) & 0xFFFF));
    ast32(hw + (((unsigned)t & 3) << 16) + selfoff, pk);
    if (lane == 0)
      __hip_atomic_fetch_add(myline, 1u, __ATOMIC_RELEASE, __HIP_MEMORY_SCOPE_AGENT);

    size_t yi = ((size_t)gb * Tlen + t) * Hdim + u0 + gunit;
    if (yf32) ((float*)ybase)[yi] = valid ? outv : 0.0f;
    else      ((short*)ybase)[yi] = valid ? f2bf(outv) : (short)0;
  }

  cbuf[(size_t)gb * Hdim + u0 + gunit] = c_state;
  const size_t sidx = (size_t)gb * Hdim + u0 + gunit;
  if (f32io) {
    ((float*)outb)[fhoff + sidx] = h_state;
    ((float*)outb)[fcoff + sidx] = c_state;
  } else {
    ((short*)outb)[fhoff + sidx] = f2bf(h_state);
    ((short*)outb)[fcoff + sidx] = f2bf(c_state);
  }
}

// ---------------------------------------------------------------------------
extern "C" void kernel_launch(void* const* d_in, const int* in_sizes, int n_in,
                              void* d_out, int out_size, void* d_ws, size_t ws_size,
                              hipStream_t stream) {
  const void* x       = d_in[0];
  const int*  lengths = (const int*)d_in[1];
  const void* Wi0     = d_in[2];
  const void* Ws0     = d_in[3];
  const void* bs0     = d_in[4];
  const void* Wi1     = d_in[5];
  const void* Ws1     = d_in[6];
  const void* bs1     = d_in[7];
  char* ws = (char*)d_ws;

  short* xbf   = (short*)(ws + WS_XBF);
  short* y0    = (short*)(ws + WS_Y0);
  short* WiT0  = (short*)(ws + WS_WIT0);
  short* WiT1  = (short*)(ws + WS_WIT1);
  short* WsT0  = (short*)(ws + WS_WST0);
  short* WsT1  = (short*)(ws + WS_WST1);
  short* pibuf = (short*)(ws + WS_PI);
  unsigned int* hw0 = (unsigned int*)(ws + WS_HW0);
  unsigned int* hw1 = (unsigned int*)(ws + WS_HW1);
  float* cbuf  = (float*)(ws + WS_CB);
  int*   dflag = (int*)(ws + WS_DFLAG);
  unsigned int* cntb = (unsigned int*)(ws + WS_CNT);

  k_detect<<<1, 256, 0, stream>>>((const short*)x, dflag);
  k_init<<<256, 256, 0, stream>>>(hw0, hw1, cntb);
  k_convert<<<2048, 256, 0, stream>>>(x, xbf, dflag);
  k_transpose<<<dim3(16, 96), 256, 0, stream>>>(Wi0, WiT0, 1024, NH6, dflag);
  k_transpose<<<dim3(16, 80), 256, 0, stream>>>(Ws0, WsT0, 1024, NH5, dflag);
  k_transpose<<<dim3(16, 96), 256, 0, stream>>>(Wi1, WiT1, 1024, NH6, dflag);
  k_transpose<<<dim3(16, 80), 256, 0, stream>>>(Ws1, WsT1, 1024, NH5, dflag);

  const unsigned int scan_lds = 48 * 1032 * 2 + 2 * 24 * 256 * 4;  // 148,224 B
  hipFuncSetAttribute((const void*)k_scan, hipFuncAttributeMaxDynamicSharedMemorySize,
                      (int)scan_lds);

  for (int layer = 0; layer < 2; ++layer) {
    const short* Asrc = (layer == 0) ? xbf : y0;
    const short* WiT  = (layer == 0) ? WiT0 : WiT1;
    const short* WsT  = (layer == 0) ? WsT0 : WsT1;
    const void*  bsp  = (layer == 0) ? bs0 : bs1;
    unsigned int* hwp = (layer == 0) ? hw0 : hw1;
    unsigned int* cntp = cntb + layer * 128;
    for (int c = 0; c < NCH; ++c) {
      k_gemm<<<dim3(32, 48), 256, 0, stream>>>(Asrc, WiT, pibuf, c * TCH);

      const short* pi_p = pibuf; const short* ws_p = WsT; const void* bs_p = bsp;
      void* y_p  = (layer == 0) ? (void*)y0 : d_out;
      int yext   = (layer == 0) ? 0 : 1;
      void* outp = d_out;
      int fh = OUT_FH + layer * 65536, fcv = OUT_FC + layer * 65536;
      unsigned int* hwq = hwp; unsigned int* cq = cntp; float* cb = cbuf;
      int tt0 = c * TCH;
      int isf = (c == 0) ? 1 : 0;
      const int* len = lengths; const int* df = dflag;
      void* args[15] = {&pi_p, &ws_p, &bs_p, &y_p, &yext, &outp, &fh, &fcv,
                        &hwq, &cq, &cb, &tt0, &isf, &len, &df};
      hipLaunchCooperativeKernel((void*)k_scan, dim3(256), dim3(256), args,
                                 scan_lds, stream);
    }
  }
}

// Round 4
// 30025.827 us; speedup vs baseline: 1.8749x; 1.8749x over previous
//
#include <hip/hip_runtime.h>

// ---------------------------------------------------------------------------
// StackedLstm: 2-layer highway LSTM, B=64, T=512, D=H=1024 (bf16 I/O)
// Recurrence sync: tagged-h dataflow + per-WAVE release flags (no RMW).
// h value+step packed in one dword, exchanged via agent-scope atomics (LLC).
// R4: gate = 1024 private flag dwords, release-stored once per wave per step
//     (release vmcnt(0) drains that wave's h publishes). Consumers spin on
//     read-only flag lines, then ONE fresh data burst (R1-proven structure);
//     per-chunk tag validation + reload spin stays as correctness floor.
// ---------------------------------------------------------------------------

#define DEVINL __device__ __forceinline__

typedef short short8v __attribute__((ext_vector_type(8)));
typedef short short4v __attribute__((ext_vector_type(4)));
typedef float f32x4 __attribute__((ext_vector_type(4)));
typedef unsigned int u32x4 __attribute__((ext_vector_type(4)));

#define Bsz   64
#define Tlen  512
#define Hdim  1024
#define NH5   5120
#define NH6   6144
#define TCH   64          // time-chunk length
#define NCH   8           // chunks per layer
#define XELT  33554432    // B*T*H elements

// d_out element offsets: y1 [B,T,H] | final_h [2,B,H] | final_c [2,B,H]
#define OUT_FH 33554432
#define OUT_FC 33685504

// workspace byte offsets (total ~233.1 MB)
#define WS_XBF    0ULL
#define WS_Y0     67108864ULL
#define WS_WIT0   134217728ULL
#define WS_WIT1   146800640ULL
#define WS_WST0   159383552ULL
#define WS_WST1   169869312ULL
#define WS_PI     180355072ULL
#define WS_HW0    230686720ULL   // 4 slots x 64 x 1024 dwords = 1 MB
#define WS_HW1    231735296ULL   // 1 MB
#define WS_CB     232783872ULL   // 256 KB fp32 c-state
#define WS_DFLAG  233046016ULL
#define WS_FLG    233047040ULL   // 2 layers x 2 grps x 512 wave-flags = 8 KB

DEVINL short f2bf(float f) {
  unsigned int u = __builtin_bit_cast(unsigned int, f);
  u += 0x7fffu + ((u >> 16) & 1u);          // round-to-nearest-even
  return (short)(u >> 16);
}
DEVINL float bf2f(short s) {
  unsigned int u = ((unsigned int)(unsigned short)s) << 16;
  return __builtin_bit_cast(float, u);
}
DEVINL float fexp2(float x) { return __builtin_amdgcn_exp2f(x); }
DEVINL float frcp(float x)  { return __builtin_amdgcn_rcpf(x); }
DEVINL float sigm(float x)  { return frcp(1.0f + fexp2(-1.44269504f * x)); }
DEVINL float tanh_(float x) { return 1.0f - 2.0f * frcp(1.0f + fexp2(2.88539008f * x)); }

DEVINL void gld_lds16(const short* g, short* lds) {
  __builtin_amdgcn_global_load_lds(
      (const __attribute__((address_space(1))) void*)g,
      (__attribute__((address_space(3))) void*)lds, 16, 0, 0);
}

DEVINL unsigned long long ald64(const unsigned long long* p) {
  return __hip_atomic_load(p, __ATOMIC_RELAXED, __HIP_MEMORY_SCOPE_AGENT);
}
DEVINL unsigned int ald32(const unsigned int* p) {
  return __hip_atomic_load(p, __ATOMIC_RELAXED, __HIP_MEMORY_SCOPE_AGENT);
}
DEVINL void ast32(unsigned int* p, unsigned int v) {
  __hip_atomic_store(p, v, __ATOMIC_RELAXED, __HIP_MEMORY_SCOPE_AGENT);
}

// all 16 tags (8 qwords, 2 dwords each) equal `want` iff AND and OR of the
// tag fields both equal it
DEVINL bool tags_ok(unsigned long long q0, unsigned long long q1,
                    unsigned long long q2, unsigned long long q3,
                    unsigned long long q4, unsigned long long q5,
                    unsigned long long q6, unsigned long long q7,
                    unsigned int want) {
  unsigned long long m = q0 & q1 & q2 & q3 & q4 & q5 & q6 & q7;
  unsigned long long x = q0 | q1 | q2 | q3 | q4 | q5 | q6 | q7;
  return ((unsigned)(m & 0xFFFFu) == want) &
         ((unsigned)((m >> 32) & 0xFFFFu) == want) &
         ((unsigned)(x & 0xFFFFu) == want) &
         ((unsigned)((x >> 32) & 0xFFFFu) == want);
}

// pick hi16 of each dword of q: {lo.hi16, hi.hi16} packed into one dword
DEVINL unsigned int hi16pair(unsigned long long q) {
  return __builtin_amdgcn_perm((unsigned int)(q >> 32), (unsigned int)q,
                               0x07060302u);
}

// ---------------------------------------------------------------------------
// Detect input dtype (bf16 never has exp==0xFF in N(0,1) data) -> dflag.
__global__ void k_detect(const short* __restrict__ x, int* dflag) {
  __shared__ int found;
  if (threadIdx.x == 0) found = 0;
  __syncthreads();
  int hit = 0;
  for (int i = threadIdx.x; i < 16384; i += 256) {
    unsigned int u = (unsigned short)x[i];
    if ((u & 0x7F80u) == 0x7F80u) hit = 1;
  }
  if (hit) atomicOr(&found, 1);
  __syncthreads();
  if (threadIdx.x == 0) *dflag = found;
}

// Zero both tagged-h rings (tags -> 0, h -> +0.0) and all wave-flags.
__global__ void k_init(unsigned int* hw0, unsigned int* hw1, unsigned int* flg) {
  const int i = (blockIdx.x * 256 + threadIdx.x) * 4;
#pragma unroll
  for (int j = 0; j < 4; ++j) { ast32(hw0 + i + j, 0u); ast32(hw1 + i + j, 0u); }
  if (blockIdx.x < 8) ast32(flg + blockIdx.x * 256 + threadIdx.x, 0u);
}

// x -> bf16 copy (converting from fp32 if detected)
__global__ void k_convert(const void* __restrict__ xin, short* __restrict__ xbf,
                          const int* __restrict__ dflag) {
  const int f32 = *dflag;
  const size_t stride = (size_t)gridDim.x * 1024;
  size_t i = ((size_t)blockIdx.x * 256 + threadIdx.x) * 4;
  for (; i < (size_t)XELT; i += stride) {
    short4v v;
    if (f32) {
      const float4 f = *(const float4*)&((const float*)xin)[i];
      v[0] = f2bf(f.x); v[1] = f2bf(f.y); v[2] = f2bf(f.z); v[3] = f2bf(f.w);
    } else {
      v = *(const short4v*)&((const short*)xin)[i];
    }
    *(short4v*)&xbf[i] = v;
  }
}

// (R,C) -> (C,R) bf16 output, dtype-flagged input, 64x64 tiles
__global__ void k_transpose(const void* __restrict__ in, short* __restrict__ out,
                            int R, int C, const int* __restrict__ dflag) {
  __shared__ short tile[64][65];
  const int f32 = *dflag;
  const int r0 = blockIdx.x << 6, c0 = blockIdx.y << 6;
  const int tid = threadIdx.x;
#pragma unroll
  for (int it = 0; it < 8; ++it) {
    int idx = (it << 8) + tid;
    int r = idx >> 5, c2 = (idx & 31) << 1;
    if (f32) {
      const float* inF = (const float*)in;
      tile[r][c2]     = f2bf(inF[(size_t)(r0 + r) * C + c0 + c2]);
      tile[r][c2 + 1] = f2bf(inF[(size_t)(r0 + r) * C + c0 + c2 + 1]);
    } else {
      int v = *(const int*)&((const short*)in)[(size_t)(r0 + r) * C + c0 + c2];
      tile[r][c2]     = (short)(v & 0xffff);
      tile[r][c2 + 1] = (short)(((unsigned)v) >> 16);
    }
  }
  __syncthreads();
#pragma unroll
  for (int it = 0; it < 8; ++it) {
    int idx = (it << 8) + tid;
    int rr = idx >> 5, k2 = (idx & 31) << 1;
    unsigned int lo = (unsigned short)tile[k2][rr];
    unsigned int hi = (unsigned short)tile[k2 + 1][rr];
    *(unsigned int*)&out[(size_t)(c0 + rr) * R + r0 + k2] = lo | (hi << 16);
  }
}

// ---------------------------------------------------------------------------
// pi_chunk[r, 0:6144] = A[row(r), :] @ Bt^T, rows map the chunk's (b, t0+tt).
__launch_bounds__(256)
__global__ void k_gemm(const short* __restrict__ A, const short* __restrict__ Bt,
                       short* __restrict__ Cmat, int t0) {
  __shared__ short ldsA[128 * 64];
  __shared__ short ldsB[128 * 64];
  const int tid = threadIdx.x, lane = tid & 63, wv = tid >> 6;
  const int wm = wv >> 1, wn = wv & 1;
  const int r0 = blockIdx.x * 128;
  const size_t brow0 = (size_t)blockIdx.y * 128;
  f32x4 acc[4][4] = {};

  for (int kk = 0; kk < Hdim; kk += 64) {
#pragma unroll
    for (int p = 0; p < 4; ++p) {
      int slot = ((wv * 4 + p) << 6) + lane;
      int m = slot >> 3, gp = slot & 7;
      int gl = gp ^ (m & 7);
      int r = r0 + m;
      size_t arow = ((size_t)(r >> 6) * Tlen + t0 + (r & 63)) * Hdim;
      gld_lds16(A + arow + kk + (gl << 3), &ldsA[(wv * 4 + p) << 9]);
      gld_lds16(Bt + (brow0 + m) * Hdim + kk + (gl << 3), &ldsB[(wv * 4 + p) << 9]);
    }
    __syncthreads();
#pragma unroll
    for (int kh = 0; kh < 2; ++kh) {
      short8v af[4], bfv[4];
      const int gl = (kh << 2) + (lane >> 4);
#pragma unroll
      for (int mt = 0; mt < 4; ++mt) {
        int m = wm * 64 + mt * 16 + (lane & 15);
        af[mt] = *(const short8v*)&ldsA[m * 64 + ((gl ^ (m & 7)) << 3)];
      }
#pragma unroll
      for (int nt = 0; nt < 4; ++nt) {
        int n = wn * 64 + nt * 16 + (lane & 15);
        bfv[nt] = *(const short8v*)&ldsB[n * 64 + ((gl ^ (n & 7)) << 3)];
      }
#pragma unroll
      for (int mt = 0; mt < 4; ++mt)
#pragma unroll
        for (int nt = 0; nt < 4; ++nt)
          acc[mt][nt] = __builtin_amdgcn_mfma_f32_16x16x32_bf16(af[mt], bfv[nt], acc[mt][nt], 0, 0, 0);
    }
    __syncthreads();
  }
#pragma unroll
  for (int mt = 0; mt < 4; ++mt)
#pragma unroll
    for (int nt = 0; nt < 4; ++nt)
#pragma unroll
      for (int q = 0; q < 4; ++q) {
        size_t row = (size_t)r0 + wm * 64 + mt * 16 + ((lane >> 4) << 2) + q;
        size_t col = brow0 + wn * 64 + nt * 16 + (lane & 15);
        Cmat[row * NH6 + col] = f2bf(acc[mt][nt][q]);
      }
}

// ---------------------------------------------------------------------------
// Persistent recurrent scan, one TCH-step chunk. 256 WGs x 256 threads.
// WG (grp, gbid): batch rows grp*32..+31, hidden units gbid*8..+7.
// h ring: hw[4][64][1024] dwords, dword = (bf16 h << 16) | ((t+1) & 0xFFFF).
// flg: per-(grp, WG, wave) flag dword, release-stored = t+1 after the wave's
// 64 h publishes. Consumer gate: min over the grp's 512 flags >= t.
__launch_bounds__(256, 1)
__global__ void k_scan(const short* __restrict__ pi, const short* __restrict__ WsT,
                       const void* __restrict__ bs, void* __restrict__ ybase, int yext,
                       void* __restrict__ outb, int fhoff, int fcoff,
                       unsigned int* hw, unsigned int* flg, float* cbuf,
                       int t0, int isfirst,
                       const int* __restrict__ lengths, const int* __restrict__ dflag) {
  extern __shared__ short smem[];
  short* Wt = smem;                                   // 48*1032 shorts
  float* psred = (float*)(smem + 48 * 1032);          // 2 x 24*256 floats

  const int tid  = threadIdx.x, lane = tid & 63, wv = tid >> 6;
  const int bid  = blockIdx.x, grp = bid >> 7, gbid = bid & 127;
  const int rb0  = grp * 32;
  const int u0   = gbid * 8;
  const int f32io = *dflag;
  const int yf32  = yext & f32io;

  // --- one-time: weight slice to LDS (cols packed n = gate*8 + unit)
  for (int n = 0; n < 40; ++n) {
    const short* src = WsT + (size_t)((n >> 3) * Hdim + u0 + (n & 7)) * Hdim;
    *(short4v*)&Wt[n * 1032 + tid * 4] = *(const short4v*)&src[tid * 4];
  }
  short4v zz = {0, 0, 0, 0};
  for (int n = 40; n < 48; ++n) *(short4v*)&Wt[n * 1032 + tid * 4] = zz;

  const int grow = tid >> 3, gunit = tid & 7;
  const int gb = rb0 + grow;
  const int mylen = lengths[gb];
  const unsigned int selfoff = ((unsigned)gb << 10) | (unsigned)(u0 + gunit);
  const unsigned int* flgg = flg + (grp << 9);        // this grp's 512 flags
  unsigned int* myflag = flg + (grp << 9) + (gbid << 2) + wv;

  float bias[5];
  int   psoff[5];
#pragma unroll
  for (int g = 0; g < 5; ++g) {
    bias[g] = f32io ? ((const float*)bs)[g * Hdim + u0 + gunit]
                    : bf2f(((const short*)bs)[g * Hdim + u0 + gunit]);
    int n = g * 8 + gunit, nt = n >> 4, cl = n & 15;
    int mt = grow >> 4, rw = grow & 15;
    int ln = ((rw >> 2) << 4) | cl, reg = rw & 3;
    psoff[g] = ((mt * 3 + nt) << 8) + (ln << 2) + reg;
  }

  // restore own state: h from ring slot (t0-1)&3 (zeros if first), c from cbuf
  float h_state = bf2f((short)(ald32(hw + (((unsigned)(t0 + 3) & 3) << 16) + selfoff) >> 16));
  float c_state = isfirst ? 0.0f : cbuf[(size_t)gb * Hdim + u0 + gunit];

  const int kb = wv << 8;                 // wave's K base (dword index)
  const int klane = (lane >> 4) << 3;

  for (int t = t0; t < t0 + TCH; ++t) {
    // pi loads first (independent of h; HBM latency hides under the wait)
    const short* pib = pi + (size_t)(gb * TCH + (t - t0)) * NH6 + u0 + gunit;
    float piv[6];
#pragma unroll
    for (int g = 0; g < 6; ++g) piv[g] = bf2f(pib[g << 10]);

    // --- flag gate: spin (read-only) until every wave of this grp has
    // released step t-1. flag value after step u is u+1, so need min >= t.
    if (t) {
      const unsigned int need = (unsigned)t;
      const unsigned int* fp = flgg + (lane << 3);
      for (;;) {
        unsigned int mn = ald32(fp);
#pragma unroll
        for (int j = 1; j < 8; ++j) {
          unsigned int v = ald32(fp + j);
          mn = v < mn ? v : mn;
        }
        if (__all((int)(mn >= need))) break;
      }
    }
    __builtin_amdgcn_sched_barrier(0);

    const unsigned long long* hs =
        (const unsigned long long*)hw + ((size_t)((t + 3) & 3) << 15);
    const unsigned int want = (unsigned)(t & 0xFFFF);
    // per-lane qword base: row (rb0 + lane&15), k = kb + klane
    const unsigned long long* pb =
        hs + (((size_t)(rb0 + (lane & 15))) << 9) + ((kb + klane) >> 1);

    // --- one fresh data burst: all 64 qwords in flight together.
    unsigned long long q[8][8];
#pragma unroll
    for (int ks = 0; ks < 8; ++ks) {
      const unsigned long long* p0 = pb + ks * 16;
#pragma unroll
      for (int j = 0; j < 4; ++j) {
        q[ks][j]     = ald64(p0 + j);
        q[ks][4 + j] = ald64(p0 + (16 << 9) + j);
      }
    }
    __builtin_amdgcn_sched_barrier(0);

    // --- validate from regs (tags = correctness floor; reload spin should
    // never be taken now that the gate guarantees freshness) + MFMA.
    f32x4 acc[2][3] = {};
#pragma unroll
    for (int ks = 0; ks < 8; ++ks) {
      bool ok = tags_ok(q[ks][0], q[ks][1], q[ks][2], q[ks][3],
                        q[ks][4], q[ks][5], q[ks][6], q[ks][7], want);
      while (!ok) {
        const unsigned long long* p0 = pb + ks * 16;
#pragma unroll
        for (int j = 0; j < 4; ++j) {
          q[ks][j]     = ald64(p0 + j);
          q[ks][4 + j] = ald64(p0 + (16 << 9) + j);
        }
        ok = tags_ok(q[ks][0], q[ks][1], q[ks][2], q[ks][3],
                     q[ks][4], q[ks][5], q[ks][6], q[ks][7], want);
      }
      u32x4 ua, ub;
#pragma unroll
      for (int j = 0; j < 4; ++j) {
        ua[j] = hi16pair(q[ks][j]);
        ub[j] = hi16pair(q[ks][4 + j]);
      }
      short8v a0 = __builtin_bit_cast(short8v, ua);
      short8v a1 = __builtin_bit_cast(short8v, ub);
      const int k = kb + (ks << 5) + klane;
#pragma unroll
      for (int nt = 0; nt < 3; ++nt) {
        short8v bfv = *(const short8v*)&Wt[(nt * 16 + (lane & 15)) * 1032 + k];
        acc[0][nt] = __builtin_amdgcn_mfma_f32_16x16x32_bf16(a0, bfv, acc[0][nt], 0, 0, 0);
        acc[1][nt] = __builtin_amdgcn_mfma_f32_16x16x32_bf16(a1, bfv, acc[1][nt], 0, 0, 0);
      }
    }

    // psred double-buffered by (t&1): no trailing barrier needed.
    float* ps_w = psred + ((t & 1) * 6144);
#pragma unroll
    for (int mt = 0; mt < 2; ++mt)
#pragma unroll
      for (int nt = 0; nt < 3; ++nt)
        *(f32x4*)&ps_w[((wv * 6 + mt * 3 + nt) << 8) + (lane << 2)] = acc[mt][nt];
    __syncthreads();

    float ps[5];
#pragma unroll
    for (int g = 0; g < 5; ++g) {
      int o = psoff[g];
      ps[g] = bias[g] + ps_w[o] + ps_w[1536 + o] + ps_w[3072 + o] + ps_w[4608 + o];
    }
    float ig = sigm(piv[0] + ps[0]);
    float fg = sigm(piv[1] + ps[1]);
    float mg = tanh_(piv[2] + ps[2]);
    float og = sigm(piv[3] + ps[3]);
    float hw_g = sigm(piv[4] + ps[4]);
    float cn  = ig * mg + fg * c_state;
    float outv = og * tanh_(cn);
    outv = hw_g * outv + (1.0f - hw_g) * piv[5];
    const bool valid = (t < mylen);
    if (valid) { c_state = cn; h_state = outv; }

    // publish h(t) tagged t+1 into ring slot t&3, then the wave's release
    // flag (drains this wave's h stores), then the y-store.
    unsigned int pk = (((unsigned)(unsigned short)f2bf(h_state)) << 16) |
                      ((unsigned)((t + 1) & 0xFFFF));
    ast32(hw + (((unsigned)t & 3) << 16) + selfoff, pk);
    if (lane == 0)
      __hip_atomic_store(myflag, (unsigned)(t + 1), __ATOMIC_RELEASE,
                         __HIP_MEMORY_SCOPE_AGENT);

    size_t yi = ((size_t)gb * Tlen + t) * Hdim + u0 + gunit;
    if (yf32) ((float*)ybase)[yi] = valid ? outv : 0.0f;
    else      ((short*)ybase)[yi] = valid ? f2bf(outv) : (short)0;
  }

  cbuf[(size_t)gb * Hdim + u0 + gunit] = c_state;
  const size_t sidx = (size_t)gb * Hdim + u0 + gunit;
  if (f32io) {
    ((float*)outb)[fhoff + sidx] = h_state;
    ((float*)outb)[fcoff + sidx] = c_state;
  } else {
    ((short*)outb)[fhoff + sidx] = f2bf(h_state);
    ((short*)outb)[fcoff + sidx] = f2bf(c_state);
  }
}

// ---------------------------------------------------------------------------
extern "C" void kernel_launch(void* const* d_in, const int* in_sizes, int n_in,
                              void* d_out, int out_size, void* d_ws, size_t ws_size,
                              hipStream_t stream) {
  const void* x       = d_in[0];
  const int*  lengths = (const int*)d_in[1];
  const void* Wi0     = d_in[2];
  const void* Ws0     = d_in[3];
  const void* bs0     = d_in[4];
  const void* Wi1     = d_in[5];
  const void* Ws1     = d_in[6];
  const void* bs1     = d_in[7];
  char* ws = (char*)d_ws;

  short* xbf   = (short*)(ws + WS_XBF);
  short* y0    = (short*)(ws + WS_Y0);
  short* WiT0  = (short*)(ws + WS_WIT0);
  short* WiT1  = (short*)(ws + WS_WIT1);
  short* WsT0  = (short*)(ws + WS_WST0);
  short* WsT1  = (short*)(ws + WS_WST1);
  short* pibuf = (short*)(ws + WS_PI);
  unsigned int* hw0 = (unsigned int*)(ws + WS_HW0);
  unsigned int* hw1 = (unsigned int*)(ws + WS_HW1);
  float* cbuf  = (float*)(ws + WS_CB);
  int*   dflag = (int*)(ws + WS_DFLAG);
  unsigned int* flgb = (unsigned int*)(ws + WS_FLG);

  k_detect<<<1, 256, 0, stream>>>((const short*)x, dflag);
  k_init<<<256, 256, 0, stream>>>(hw0, hw1, flgb);
  k_convert<<<2048, 256, 0, stream>>>(x, xbf, dflag);
  k_transpose<<<dim3(16, 96), 256, 0, stream>>>(Wi0, WiT0, 1024, NH6, dflag);
  k_transpose<<<dim3(16, 80), 256, 0, stream>>>(Ws0, WsT0, 1024, NH5, dflag);
  k_transpose<<<dim3(16, 96), 256, 0, stream>>>(Wi1, WiT1, 1024, NH6, dflag);
  k_transpose<<<dim3(16, 80), 256, 0, stream>>>(Ws1, WsT1, 1024, NH5, dflag);

  const unsigned int scan_lds = 48 * 1032 * 2 + 2 * 24 * 256 * 4;  // 148,224 B
  hipFuncSetAttribute((const void*)k_scan, hipFuncAttributeMaxDynamicSharedMemorySize,
                      (int)scan_lds);

  for (int layer = 0; layer < 2; ++layer) {
    const short* Asrc = (layer == 0) ? xbf : y0;
    const short* WiT  = (layer == 0) ? WiT0 : WiT1;
    const short* WsT  = (layer == 0) ? WsT0 : WsT1;
    const void*  bsp  = (layer == 0) ? bs0 : bs1;
    unsigned int* hwp = (layer == 0) ? hw0 : hw1;
    unsigned int* flgp = flgb + layer * 1024;
    for (int c = 0; c < NCH; ++c) {
      k_gemm<<<dim3(32, 48), 256, 0, stream>>>(Asrc, WiT, pibuf, c * TCH);

      const short* pi_p = pibuf; const short* ws_p = WsT; const void* bs_p = bsp;
      void* y_p  = (layer == 0) ? (void*)y0 : d_out;
      int yext   = (layer == 0) ? 0 : 1;
      void* outp = d_out;
      int fh = OUT_FH + layer * 65536, fcv = OUT_FC + layer * 65536;
      unsigned int* hwq = hwp; unsigned int* fq = flgp; float* cb = cbuf;
      int tt0 = c * TCH;
      int isf = (c == 0) ? 1 : 0;
      const int* len = lengths; const int* df = dflag;
      void* args[15] = {&pi_p, &ws_p, &bs_p, &y_p, &yext, &outp, &fh, &fcv,
                        &hwq, &fq, &cb, &tt0, &isf, &len, &df};
      hipLaunchCooperativeKernel((void*)k_scan, dim3(256), dim3(256), args,
                                 scan_lds, stream);
    }
  }
}

// Round 5
// 13618.640 us; speedup vs baseline: 4.1338x; 2.2048x over previous
//
#include <hip/hip_runtime.h>

// ---------------------------------------------------------------------------
// StackedLstm: 2-layer highway LSTM, B=64, T=512, D=H=1024 (bf16 I/O)
// Recurrence sync: tagged-h dataflow + per-WAVE RELAXED hint flags.
// h value+step packed in one dword, exchanged via agent-scope atomics (LLC).
// R5: flag store RELEASE -> RELAXED. Agent-scope release forces an L2
//     writeback on gfx950 (per-XCD L2 non-coherent) -- ~35us/step of pure
//     fence cost in R4. Tags-in-data are the correctness floor (per-chunk
//     validate + reload spin); flags are only a performance hint now.
// ---------------------------------------------------------------------------

#define DEVINL __device__ __forceinline__

typedef short short8v __attribute__((ext_vector_type(8)));
typedef short short4v __attribute__((ext_vector_type(4)));
typedef float f32x4 __attribute__((ext_vector_type(4)));
typedef unsigned int u32x4 __attribute__((ext_vector_type(4)));

#define Bsz   64
#define Tlen  512
#define Hdim  1024
#define NH5   5120
#define NH6   6144
#define TCH   64          // time-chunk length
#define NCH   8           // chunks per layer
#define XELT  33554432    // B*T*H elements

// d_out element offsets: y1 [B,T,H] | final_h [2,B,H] | final_c [2,B,H]
#define OUT_FH 33554432
#define OUT_FC 33685504

// workspace byte offsets (total ~233.1 MB)
#define WS_XBF    0ULL
#define WS_Y0     67108864ULL
#define WS_WIT0   134217728ULL
#define WS_WIT1   146800640ULL
#define WS_WST0   159383552ULL
#define WS_WST1   169869312ULL
#define WS_PI     180355072ULL
#define WS_HW0    230686720ULL   // 4 slots x 64 x 1024 dwords = 1 MB
#define WS_HW1    231735296ULL   // 1 MB
#define WS_CB     232783872ULL   // 256 KB fp32 c-state
#define WS_DFLAG  233046016ULL
#define WS_FLG    233047040ULL   // 2 layers x 2 grps x 512 wave-flags = 8 KB

DEVINL short f2bf(float f) {
  unsigned int u = __builtin_bit_cast(unsigned int, f);
  u += 0x7fffu + ((u >> 16) & 1u);          // round-to-nearest-even
  return (short)(u >> 16);
}
DEVINL float bf2f(short s) {
  unsigned int u = ((unsigned int)(unsigned short)s) << 16;
  return __builtin_bit_cast(float, u);
}
DEVINL float fexp2(float x) { return __builtin_amdgcn_exp2f(x); }
DEVINL float frcp(float x)  { return __builtin_amdgcn_rcpf(x); }
DEVINL float sigm(float x)  { return frcp(1.0f + fexp2(-1.44269504f * x)); }
DEVINL float tanh_(float x) { return 1.0f - 2.0f * frcp(1.0f + fexp2(2.88539008f * x)); }

DEVINL void gld_lds16(const short* g, short* lds) {
  __builtin_amdgcn_global_load_lds(
      (const __attribute__((address_space(1))) void*)g,
      (__attribute__((address_space(3))) void*)lds, 16, 0, 0);
}

DEVINL unsigned long long ald64(const unsigned long long* p) {
  return __hip_atomic_load(p, __ATOMIC_RELAXED, __HIP_MEMORY_SCOPE_AGENT);
}
DEVINL unsigned int ald32(const unsigned int* p) {
  return __hip_atomic_load(p, __ATOMIC_RELAXED, __HIP_MEMORY_SCOPE_AGENT);
}
DEVINL void ast32(unsigned int* p, unsigned int v) {
  __hip_atomic_store(p, v, __ATOMIC_RELAXED, __HIP_MEMORY_SCOPE_AGENT);
}

// all 16 tags (8 qwords, 2 dwords each) equal `want` iff AND and OR of the
// tag fields both equal it
DEVINL bool tags_ok(unsigned long long q0, unsigned long long q1,
                    unsigned long long q2, unsigned long long q3,
                    unsigned long long q4, unsigned long long q5,
                    unsigned long long q6, unsigned long long q7,
                    unsigned int want) {
  unsigned long long m = q0 & q1 & q2 & q3 & q4 & q5 & q6 & q7;
  unsigned long long x = q0 | q1 | q2 | q3 | q4 | q5 | q6 | q7;
  return ((unsigned)(m & 0xFFFFu) == want) &
         ((unsigned)((m >> 32) & 0xFFFFu) == want) &
         ((unsigned)(x & 0xFFFFu) == want) &
         ((unsigned)((x >> 32) & 0xFFFFu) == want);
}

// pick hi16 of each dword of q: {lo.hi16, hi.hi16} packed into one dword
DEVINL unsigned int hi16pair(unsigned long long q) {
  return __builtin_amdgcn_perm((unsigned int)(q >> 32), (unsigned int)q,
                               0x07060302u);
}

// ---------------------------------------------------------------------------
// Detect input dtype (bf16 never has exp==0xFF in N(0,1) data) -> dflag.
__global__ void k_detect(const short* __restrict__ x, int* dflag) {
  __shared__ int found;
  if (threadIdx.x == 0) found = 0;
  __syncthreads();
  int hit = 0;
  for (int i = threadIdx.x; i < 16384; i += 256) {
    unsigned int u = (unsigned short)x[i];
    if ((u & 0x7F80u) == 0x7F80u) hit = 1;
  }
  if (hit) atomicOr(&found, 1);
  __syncthreads();
  if (threadIdx.x == 0) *dflag = found;
}

// Zero both tagged-h rings (tags -> 0, h -> +0.0) and all wave-flags.
__global__ void k_init(unsigned int* hw0, unsigned int* hw1, unsigned int* flg) {
  const int i = (blockIdx.x * 256 + threadIdx.x) * 4;
#pragma unroll
  for (int j = 0; j < 4; ++j) { ast32(hw0 + i + j, 0u); ast32(hw1 + i + j, 0u); }
  if (blockIdx.x < 8) ast32(flg + blockIdx.x * 256 + threadIdx.x, 0u);
}

// x -> bf16 copy (converting from fp32 if detected)
__global__ void k_convert(const void* __restrict__ xin, short* __restrict__ xbf,
                          const int* __restrict__ dflag) {
  const int f32 = *dflag;
  const size_t stride = (size_t)gridDim.x * 1024;
  size_t i = ((size_t)blockIdx.x * 256 + threadIdx.x) * 4;
  for (; i < (size_t)XELT; i += stride) {
    short4v v;
    if (f32) {
      const float4 f = *(const float4*)&((const float*)xin)[i];
      v[0] = f2bf(f.x); v[1] = f2bf(f.y); v[2] = f2bf(f.z); v[3] = f2bf(f.w);
    } else {
      v = *(const short4v*)&((const short*)xin)[i];
    }
    *(short4v*)&xbf[i] = v;
  }
}

// (R,C) -> (C,R) bf16 output, dtype-flagged input, 64x64 tiles
__global__ void k_transpose(const void* __restrict__ in, short* __restrict__ out,
                            int R, int C, const int* __restrict__ dflag) {
  __shared__ short tile[64][65];
  const int f32 = *dflag;
  const int r0 = blockIdx.x << 6, c0 = blockIdx.y << 6;
  const int tid = threadIdx.x;
#pragma unroll
  for (int it = 0; it < 8; ++it) {
    int idx = (it << 8) + tid;
    int r = idx >> 5, c2 = (idx & 31) << 1;
    if (f32) {
      const float* inF = (const float*)in;
      tile[r][c2]     = f2bf(inF[(size_t)(r0 + r) * C + c0 + c2]);
      tile[r][c2 + 1] = f2bf(inF[(size_t)(r0 + r) * C + c0 + c2 + 1]);
    } else {
      int v = *(const int*)&((const short*)in)[(size_t)(r0 + r) * C + c0 + c2];
      tile[r][c2]     = (short)(v & 0xffff);
      tile[r][c2 + 1] = (short)(((unsigned)v) >> 16);
    }
  }
  __syncthreads();
#pragma unroll
  for (int it = 0; it < 8; ++it) {
    int idx = (it << 8) + tid;
    int rr = idx >> 5, k2 = (idx & 31) << 1;
    unsigned int lo = (unsigned short)tile[k2][rr];
    unsigned int hi = (unsigned short)tile[k2 + 1][rr];
    *(unsigned int*)&out[(size_t)(c0 + rr) * R + r0 + k2] = lo | (hi << 16);
  }
}

// ---------------------------------------------------------------------------
// pi_chunk[r, 0:6144] = A[row(r), :] @ Bt^T, rows map the chunk's (b, t0+tt).
__launch_bounds__(256)
__global__ void k_gemm(const short* __restrict__ A, const short* __restrict__ Bt,
                       short* __restrict__ Cmat, int t0) {
  __shared__ short ldsA[128 * 64];
  __shared__ short ldsB[128 * 64];
  const int tid = threadIdx.x, lane = tid & 63, wv = tid >> 6;
  const int wm = wv >> 1, wn = wv & 1;
  const int r0 = blockIdx.x * 128;
  const size_t brow0 = (size_t)blockIdx.y * 128;
  f32x4 acc[4][4] = {};

  for (int kk = 0; kk < Hdim; kk += 64) {
#pragma unroll
    for (int p = 0; p < 4; ++p) {
      int slot = ((wv * 4 + p) << 6) + lane;
      int m = slot >> 3, gp = slot & 7;
      int gl = gp ^ (m & 7);
      int r = r0 + m;
      size_t arow = ((size_t)(r >> 6) * Tlen + t0 + (r & 63)) * Hdim;
      gld_lds16(A + arow + kk + (gl << 3), &ldsA[(wv * 4 + p) << 9]);
      gld_lds16(Bt + (brow0 + m) * Hdim + kk + (gl << 3), &ldsB[(wv * 4 + p) << 9]);
    }
    __syncthreads();
#pragma unroll
    for (int kh = 0; kh < 2; ++kh) {
      short8v af[4], bfv[4];
      const int gl = (kh << 2) + (lane >> 4);
#pragma unroll
      for (int mt = 0; mt < 4; ++mt) {
        int m = wm * 64 + mt * 16 + (lane & 15);
        af[mt] = *(const short8v*)&ldsA[m * 64 + ((gl ^ (m & 7)) << 3)];
      }
#pragma unroll
      for (int nt = 0; nt < 4; ++nt) {
        int n = wn * 64 + nt * 16 + (lane & 15);
        bfv[nt] = *(const short8v*)&ldsB[n * 64 + ((gl ^ (n & 7)) << 3)];
      }
#pragma unroll
      for (int mt = 0; mt < 4; ++mt)
#pragma unroll
        for (int nt = 0; nt < 4; ++nt)
          acc[mt][nt] = __builtin_amdgcn_mfma_f32_16x16x32_bf16(af[mt], bfv[nt], acc[mt][nt], 0, 0, 0);
    }
    __syncthreads();
  }
#pragma unroll
  for (int mt = 0; mt < 4; ++mt)
#pragma unroll
    for (int nt = 0; nt < 4; ++nt)
#pragma unroll
      for (int q = 0; q < 4; ++q) {
        size_t row = (size_t)r0 + wm * 64 + mt * 16 + ((lane >> 4) << 2) + q;
        size_t col = brow0 + wn * 64 + nt * 16 + (lane & 15);
        Cmat[row * NH6 + col] = f2bf(acc[mt][nt][q]);
      }
}

// ---------------------------------------------------------------------------
// Persistent recurrent scan, one TCH-step chunk. 256 WGs x 256 threads.
// WG (grp, gbid): batch rows grp*32..+31, hidden units gbid*8..+7.
// h ring: hw[4][64][1024] dwords, dword = (bf16 h << 16) | ((t+1) & 0xFFFF).
// flg: per-(grp, WG, wave) flag dword, RELAXED-stored = t+1 after the wave's
// h publishes (hint only; correctness = tags). Gate: min over 512 flags >= t.
__launch_bounds__(256, 1)
__global__ void k_scan(const short* __restrict__ pi, const short* __restrict__ WsT,
                       const void* __restrict__ bs, void* __restrict__ ybase, int yext,
                       void* __restrict__ outb, int fhoff, int fcoff,
                       unsigned int* hw, unsigned int* flg, float* cbuf,
                       int t0, int isfirst,
                       const int* __restrict__ lengths, const int* __restrict__ dflag) {
  extern __shared__ short smem[];
  short* Wt = smem;                                   // 48*1032 shorts
  float* psred = (float*)(smem + 48 * 1032);          // 2 x 24*256 floats

  const int tid  = threadIdx.x, lane = tid & 63, wv = tid >> 6;
  const int bid  = blockIdx.x, grp = bid >> 7, gbid = bid & 127;
  const int rb0  = grp * 32;
  const int u0   = gbid * 8;
  const int f32io = *dflag;
  const int yf32  = yext & f32io;

  // --- one-time: weight slice to LDS (cols packed n = gate*8 + unit)
  for (int n = 0; n < 40; ++n) {
    const short* src = WsT + (size_t)((n >> 3) * Hdim + u0 + (n & 7)) * Hdim;
    *(short4v*)&Wt[n * 1032 + tid * 4] = *(const short4v*)&src[tid * 4];
  }
  short4v zz = {0, 0, 0, 0};
  for (int n = 40; n < 48; ++n) *(short4v*)&Wt[n * 1032 + tid * 4] = zz;

  const int grow = tid >> 3, gunit = tid & 7;
  const int gb = rb0 + grow;
  const int mylen = lengths[gb];
  const unsigned int selfoff = ((unsigned)gb << 10) | (unsigned)(u0 + gunit);
  const unsigned int* flgg = flg + (grp << 9);        // this grp's 512 flags
  unsigned int* myflag = flg + (grp << 9) + (gbid << 2) + wv;

  float bias[5];
  int   psoff[5];
#pragma unroll
  for (int g = 0; g < 5; ++g) {
    bias[g] = f32io ? ((const float*)bs)[g * Hdim + u0 + gunit]
                    : bf2f(((const short*)bs)[g * Hdim + u0 + gunit]);
    int n = g * 8 + gunit, nt = n >> 4, cl = n & 15;
    int mt = grow >> 4, rw = grow & 15;
    int ln = ((rw >> 2) << 4) | cl, reg = rw & 3;
    psoff[g] = ((mt * 3 + nt) << 8) + (ln << 2) + reg;
  }

  // restore own state: h from ring slot (t0-1)&3 (zeros if first), c from cbuf
  float h_state = bf2f((short)(ald32(hw + (((unsigned)(t0 + 3) & 3) << 16) + selfoff) >> 16));
  float c_state = isfirst ? 0.0f : cbuf[(size_t)gb * Hdim + u0 + gunit];

  const int kb = wv << 8;                 // wave's K base (dword index)
  const int klane = (lane >> 4) << 3;

  for (int t = t0; t < t0 + TCH; ++t) {
    // pi loads first (independent of h; HBM latency hides under the wait)
    const short* pib = pi + (size_t)(gb * TCH + (t - t0)) * NH6 + u0 + gunit;
    float piv[6];
#pragma unroll
    for (int g = 0; g < 6; ++g) piv[g] = bf2f(pib[g << 10]);

    // --- flag gate (hint): spin (read-only) until every wave of this grp
    // appears to have finished step t-1. flag after step u is u+1.
    if (t) {
      const unsigned int need = (unsigned)t;
      const unsigned int* fp = flgg + (lane << 3);
      for (;;) {
        unsigned int mn = ald32(fp);
#pragma unroll
        for (int j = 1; j < 8; ++j) {
          unsigned int v = ald32(fp + j);
          mn = v < mn ? v : mn;
        }
        if (__all((int)(mn >= need))) break;
      }
    }
    __builtin_amdgcn_sched_barrier(0);

    const unsigned long long* hs =
        (const unsigned long long*)hw + ((size_t)((t + 3) & 3) << 15);
    const unsigned int want = (unsigned)(t & 0xFFFF);
    // per-lane qword base: row (rb0 + lane&15), k = kb + klane
    const unsigned long long* pb =
        hs + (((size_t)(rb0 + (lane & 15))) << 9) + ((kb + klane) >> 1);

    // --- one fresh data burst: all 64 qwords in flight together.
    unsigned long long q[8][8];
#pragma unroll
    for (int ks = 0; ks < 8; ++ks) {
      const unsigned long long* p0 = pb + ks * 16;
#pragma unroll
      for (int j = 0; j < 4; ++j) {
        q[ks][j]     = ald64(p0 + j);
        q[ks][4 + j] = ald64(p0 + (16 << 9) + j);
      }
    }
    __builtin_amdgcn_sched_barrier(0);

    // --- validate from regs (tags = correctness floor; reload spin is the
    // rare path: flag/data store reordering at LLC) + MFMA.
    f32x4 acc[2][3] = {};
#pragma unroll
    for (int ks = 0; ks < 8; ++ks) {
      bool ok = tags_ok(q[ks][0], q[ks][1], q[ks][2], q[ks][3],
                        q[ks][4], q[ks][5], q[ks][6], q[ks][7], want);
      while (!ok) {
        const unsigned long long* p0 = pb + ks * 16;
#pragma unroll
        for (int j = 0; j < 4; ++j) {
          q[ks][j]     = ald64(p0 + j);
          q[ks][4 + j] = ald64(p0 + (16 << 9) + j);
        }
        ok = tags_ok(q[ks][0], q[ks][1], q[ks][2], q[ks][3],
                     q[ks][4], q[ks][5], q[ks][6], q[ks][7], want);
      }
      u32x4 ua, ub;
#pragma unroll
      for (int j = 0; j < 4; ++j) {
        ua[j] = hi16pair(q[ks][j]);
        ub[j] = hi16pair(q[ks][4 + j]);
      }
      short8v a0 = __builtin_bit_cast(short8v, ua);
      short8v a1 = __builtin_bit_cast(short8v, ub);
      const int k = kb + (ks << 5) + klane;
#pragma unroll
      for (int nt = 0; nt < 3; ++nt) {
        short8v bfv = *(const short8v*)&Wt[(nt * 16 + (lane & 15)) * 1032 + k];
        acc[0][nt] = __builtin_amdgcn_mfma_f32_16x16x32_bf16(a0, bfv, acc[0][nt], 0, 0, 0);
        acc[1][nt] = __builtin_amdgcn_mfma_f32_16x16x32_bf16(a1, bfv, acc[1][nt], 0, 0, 0);
      }
    }

    // psred double-buffered by (t&1): no trailing barrier needed.
    float* ps_w = psred + ((t & 1) * 6144);
#pragma unroll
    for (int mt = 0; mt < 2; ++mt)
#pragma unroll
      for (int nt = 0; nt < 3; ++nt)
        *(f32x4*)&ps_w[((wv * 6 + mt * 3 + nt) << 8) + (lane << 2)] = acc[mt][nt];
    __syncthreads();

    float ps[5];
#pragma unroll
    for (int g = 0; g < 5; ++g) {
      int o = psoff[g];
      ps[g] = bias[g] + ps_w[o] + ps_w[1536 + o] + ps_w[3072 + o] + ps_w[4608 + o];
    }
    float ig = sigm(piv[0] + ps[0]);
    float fg = sigm(piv[1] + ps[1]);
    float mg = tanh_(piv[2] + ps[2]);
    float og = sigm(piv[3] + ps[3]);
    float hw_g = sigm(piv[4] + ps[4]);
    float cn  = ig * mg + fg * c_state;
    float outv = og * tanh_(cn);
    outv = hw_g * outv + (1.0f - hw_g) * piv[5];
    const bool valid = (t < mylen);
    if (valid) { c_state = cn; h_state = outv; }

    // publish h(t) tagged t+1 into ring slot t&3 (atomic dword: tag+data
    // together), then the wave's RELAXED hint flag, then the y-store.
    unsigned int pk = (((unsigned)(unsigned short)f2bf(h_state)) << 16) |
                      ((unsigned)((t + 1) & 0xFFFF));
    ast32(hw + (((unsigned)t & 3) << 16) + selfoff, pk);
    if (lane == 0)
      __hip_atomic_store(myflag, (unsigned)(t + 1), __ATOMIC_RELAXED,
                         __HIP_MEMORY_SCOPE_AGENT);

    size_t yi = ((size_t)gb * Tlen + t) * Hdim + u0 + gunit;
    if (yf32) ((float*)ybase)[yi] = valid ? outv : 0.0f;
    else      ((short*)ybase)[yi] = valid ? f2bf(outv) : (short)0;
  }

  cbuf[(size_t)gb * Hdim + u0 + gunit] = c_state;
  const size_t sidx = (size_t)gb * Hdim + u0 + gunit;
  if (f32io) {
    ((float*)outb)[fhoff + sidx] = h_state;
    ((float*)outb)[fcoff + sidx] = c_state;
  } else {
    ((short*)outb)[fhoff + sidx] = f2bf(h_state);
    ((short*)outb)[fcoff + sidx] = f2bf(c_state);
  }
}

// ---------------------------------------------------------------------------
extern "C" void kernel_launch(void* const* d_in, const int* in_sizes, int n_in,
                              void* d_out, int out_size, void* d_ws, size_t ws_size,
                              hipStream_t stream) {
  const void* x       = d_in[0];
  const int*  lengths = (const int*)d_in[1];
  const void* Wi0     = d_in[2];
  const void* Ws0     = d_in[3];
  const void* bs0     = d_in[4];
  const void* Wi1     = d_in[5];
  const void* Ws1     = d_in[6];
  const void* bs1     = d_in[7];
  char* ws = (char*)d_ws;

  short* xbf   = (short*)(ws + WS_XBF);
  short* y0    = (short*)(ws + WS_Y0);
  short* WiT0  = (short*)(ws + WS_WIT0);
  short* WiT1  = (short*)(ws + WS_WIT1);
  short* WsT0  = (short*)(ws + WS_WST0);
  short* WsT1  = (short*)(ws + WS_WST1);
  short* pibuf = (short*)(ws + WS_PI);
  unsigned int* hw0 = (unsigned int*)(ws + WS_HW0);
  unsigned int* hw1 = (unsigned int*)(ws + WS_HW1);
  float* cbuf  = (float*)(ws + WS_CB);
  int*   dflag = (int*)(ws + WS_DFLAG);
  unsigned int* flgb = (unsigned int*)(ws + WS_FLG);

  k_detect<<<1, 256, 0, stream>>>((const short*)x, dflag);
  k_init<<<256, 256, 0, stream>>>(hw0, hw1, flgb);
  k_convert<<<2048, 256, 0, stream>>>(x, xbf, dflag);
  k_transpose<<<dim3(16, 96), 256, 0, stream>>>(Wi0, WiT0, 1024, NH6, dflag);
  k_transpose<<<dim3(16, 80), 256, 0, stream>>>(Ws0, WsT0, 1024, NH5, dflag);
  k_transpose<<<dim3(16, 96), 256, 0, stream>>>(Wi1, WiT1, 1024, NH6, dflag);
  k_transpose<<<dim3(16, 80), 256, 0, stream>>>(Ws1, WsT1, 1024, NH5, dflag);

  const unsigned int scan_lds = 48 * 1032 * 2 + 2 * 24 * 256 * 4;  // 148,224 B
  hipFuncSetAttribute((const void*)k_scan, hipFuncAttributeMaxDynamicSharedMemorySize,
                      (int)scan_lds);

  for (int layer = 0; layer < 2; ++layer) {
    const short* Asrc = (layer == 0) ? xbf : y0;
    const short* WiT  = (layer == 0) ? WiT0 : WiT1;
    const short* WsT  = (layer == 0) ? WsT0 : WsT1;
    const void*  bsp  = (layer == 0) ? bs0 : bs1;
    unsigned int* hwp = (layer == 0) ? hw0 : hw1;
    unsigned int* flgp = flgb + layer * 1024;
    for (int c = 0; c < NCH; ++c) {
      k_gemm<<<dim3(32, 48), 256, 0, stream>>>(Asrc, WiT, pibuf, c * TCH);

      const short* pi_p = pibuf; const short* ws_p = WsT; const void* bs_p = bsp;
      void* y_p  = (layer == 0) ? (void*)y0 : d_out;
      int yext   = (layer == 0) ? 0 : 1;
      void* outp = d_out;
      int fh = OUT_FH + layer * 65536, fcv = OUT_FC + layer * 65536;
      unsigned int* hwq = hwp; unsigned int* fq = flgp; float* cb = cbuf;
      int tt0 = c * TCH;
      int isf = (c == 0) ? 1 : 0;
      const int* len = lengths; const int* df = dflag;
      void* args[15] = {&pi_p, &ws_p, &bs_p, &y_p, &yext, &outp, &fh, &fcv,
                        &hwq, &fq, &cb, &tt0, &isf, &len, &df};
      hipLaunchCooperativeKernel((void*)k_scan, dim3(256), dim3(256), args,
                                 scan_lds, stream);
    }
  }
}

// Round 6
// 7574.695 us; speedup vs baseline: 7.4322x; 1.7979x over previous
//
#include <hip/hip_runtime.h>

// ---------------------------------------------------------------------------
// StackedLstm: 2-layer highway LSTM, B=64, T=512, D=H=1024 (bf16 I/O)
// Recurrence sync: tagged-h dataflow (R0 structure: per-chunk tag-poll, no
// gate, no flags). h value+step packed per dword via agent-scope LLC access.
// R6: (1) chunk-order stagger by gbid&7 (spreads LLC hot-spot 8x),
//     (2) dwordx4 sc0 sc1 poll loads (2x fewer requests),
//     (3) depth-2 software pipeline with counted vmcnt (RT overlapped).
// ---------------------------------------------------------------------------

#define DEVINL __device__ __forceinline__

typedef short short8v __attribute__((ext_vector_type(8)));
typedef short short4v __attribute__((ext_vector_type(4)));
typedef float f32x4 __attribute__((ext_vector_type(4)));
typedef unsigned int u32x4 __attribute__((ext_vector_type(4)));

#define Bsz   64
#define Tlen  512
#define Hdim  1024
#define NH5   5120
#define NH6   6144
#define TCH   64          // time-chunk length
#define NCH   8           // chunks per layer
#define XELT  33554432    // B*T*H elements

// d_out element offsets: y1 [B,T,H] | final_h [2,B,H] | final_c [2,B,H]
#define OUT_FH 33554432
#define OUT_FC 33685504

// workspace byte offsets (total ~233.1 MB)
#define WS_XBF    0ULL
#define WS_Y0     67108864ULL
#define WS_WIT0   134217728ULL
#define WS_WIT1   146800640ULL
#define WS_WST0   159383552ULL
#define WS_WST1   169869312ULL
#define WS_PI     180355072ULL
#define WS_HW0    230686720ULL   // 4 slots x 64 x 1024 dwords = 1 MB
#define WS_HW1    231735296ULL   // 1 MB
#define WS_CB     232783872ULL   // 256 KB fp32 c-state
#define WS_DFLAG  233046016ULL

DEVINL short f2bf(float f) {
  unsigned int u = __builtin_bit_cast(unsigned int, f);
  u += 0x7fffu + ((u >> 16) & 1u);          // round-to-nearest-even
  return (short)(u >> 16);
}
DEVINL float bf2f(short s) {
  unsigned int u = ((unsigned int)(unsigned short)s) << 16;
  return __builtin_bit_cast(float, u);
}
DEVINL float fexp2(float x) { return __builtin_amdgcn_exp2f(x); }
DEVINL float frcp(float x)  { return __builtin_amdgcn_rcpf(x); }
DEVINL float sigm(float x)  { return frcp(1.0f + fexp2(-1.44269504f * x)); }
DEVINL float tanh_(float x) { return 1.0f - 2.0f * frcp(1.0f + fexp2(2.88539008f * x)); }

DEVINL void gld_lds16(const short* g, short* lds) {
  __builtin_amdgcn_global_load_lds(
      (const __attribute__((address_space(1))) void*)g,
      (__attribute__((address_space(3))) void*)lds, 16, 0, 0);
}

DEVINL unsigned int ald32(const unsigned int* p) {
  return __hip_atomic_load(p, __ATOMIC_RELAXED, __HIP_MEMORY_SCOPE_AGENT);
}
DEVINL void ast32(unsigned int* p, unsigned int v) {
  __hip_atomic_store(p, v, __ATOMIC_RELAXED, __HIP_MEMORY_SCOPE_AGENT);
}

DEVINL u32x4 vzero4() { u32x4 v = {0u, 0u, 0u, 0u}; return v; }

// All 16 tags (16 dwords, tag in low16 of each) equal `want` iff the AND and
// the OR of the tag fields both equal it.
DEVINL bool vtags_ok(u32x4 b0, u32x4 b1, u32x4 b2, u32x4 b3, unsigned want) {
  u32x4 m = b0 & b1 & b2 & b3;
  u32x4 x = b0 | b1 | b2 | b3;
  unsigned mm = m[0] & m[1] & m[2] & m[3];
  unsigned xx = x[0] | x[1] | x[2] | x[3];
  return (((mm ^ want) | (xx ^ want)) & 0xFFFFu) == 0u;
}

// 4x 16B LLC-coherent loads: 32B at _a0 (rows lane&15) + 32B at _a1 (+16 rows)
#define HLOAD(b0, b1, b2, b3, cc) do {                                       \
    const char* _a0 = pbb + ((size_t)(cc) << 7);                             \
    const char* _a1 = _a0 + 65536;                                           \
    asm volatile(                                                            \
      "global_load_dwordx4 %0, %4, off sc0 sc1\n\t"                          \
      "global_load_dwordx4 %1, %4, off offset:16 sc0 sc1\n\t"                \
      "global_load_dwordx4 %2, %5, off sc0 sc1\n\t"                          \
      "global_load_dwordx4 %3, %5, off offset:16 sc0 sc1"                    \
      : "+v"(b0), "+v"(b1), "+v"(b2), "+v"(b3)                               \
      : "v"(_a0), "v"(_a1) : "memory");                                      \
  } while (0)

// zero regs first: a premature wait can never false-pass on stale tags
// (zero tag != want for t>0; at t=0 zeros ARE the correct h(-1)=0 data)
#define ZISSUE(b0, b1, b2, b3, cc) do {                                      \
    b0 = vzero4(); b1 = vzero4(); b2 = vzero4(); b3 = vzero4();              \
    HLOAD(b0, b1, b2, b3, cc);                                               \
  } while (0)

#define WAITCNT_(n) asm volatile("s_waitcnt vmcnt(" #n ")" ::: "memory")
#define WAITCNT(n) WAITCNT_(n)

// unpack hi16 h-values -> bf16x8 frags, 6 MFMAs for this chunk
#define MMAC(b0, b1, b2, b3, cc) do {                                        \
    u32x4 _ua, _ub;                                                          \
    _ua[0] = __builtin_amdgcn_perm(b0[1], b0[0], 0x07060302u);               \
    _ua[1] = __builtin_amdgcn_perm(b0[3], b0[2], 0x07060302u);               \
    _ua[2] = __builtin_amdgcn_perm(b1[1], b1[0], 0x07060302u);               \
    _ua[3] = __builtin_amdgcn_perm(b1[3], b1[2], 0x07060302u);               \
    _ub[0] = __builtin_amdgcn_perm(b2[1], b2[0], 0x07060302u);               \
    _ub[1] = __builtin_amdgcn_perm(b2[3], b2[2], 0x07060302u);               \
    _ub[2] = __builtin_amdgcn_perm(b3[1], b3[0], 0x07060302u);               \
    _ub[3] = __builtin_amdgcn_perm(b3[3], b3[2], 0x07060302u);               \
    short8v _a0 = __builtin_bit_cast(short8v, _ua);                          \
    short8v _a1 = __builtin_bit_cast(short8v, _ub);                          \
    const int _k = kb + ((cc) << 5) + klane;                                 \
    _Pragma("unroll")                                                        \
    for (int _nt = 0; _nt < 3; ++_nt) {                                      \
      short8v _bf = *(const short8v*)&Wt[(_nt * 16 + (lane & 15)) * 1032 + _k]; \
      acc[0][_nt] = __builtin_amdgcn_mfma_f32_16x16x32_bf16(_a0, _bf, acc[0][_nt], 0, 0, 0); \
      acc[1][_nt] = __builtin_amdgcn_mfma_f32_16x16x32_bf16(_a1, _bf, acc[1][_nt], 0, 0, 0); \
    }                                                                        \
  } while (0)

// wait (counted) -> validate (respin = cold path, self-healing) -> MFMA
#define PROC(b0, b1, b2, b3, cc, WN) do {                                    \
    WAITCNT(WN);                                                             \
    __builtin_amdgcn_sched_barrier(0);                                       \
    if (!vtags_ok(b0, b1, b2, b3, want)) {                                   \
      do {                                                                   \
        HLOAD(b0, b1, b2, b3, cc);                                           \
        WAITCNT(0);                                                          \
        __builtin_amdgcn_sched_barrier(0);                                   \
      } while (!vtags_ok(b0, b1, b2, b3, want));                             \
    }                                                                        \
    MMAC(b0, b1, b2, b3, cc);                                                \
  } while (0)

// ---------------------------------------------------------------------------
// Detect input dtype (bf16 never has exp==0xFF in N(0,1) data) -> dflag.
__global__ void k_detect(const short* __restrict__ x, int* dflag) {
  __shared__ int found;
  if (threadIdx.x == 0) found = 0;
  __syncthreads();
  int hit = 0;
  for (int i = threadIdx.x; i < 16384; i += 256) {
    unsigned int u = (unsigned short)x[i];
    if ((u & 0x7F80u) == 0x7F80u) hit = 1;
  }
  if (hit) atomicOr(&found, 1);
  __syncthreads();
  if (threadIdx.x == 0) *dflag = found;
}

// Zero both tagged-h rings (tags -> 0, h -> +0.0).
__global__ void k_init(unsigned int* hw0, unsigned int* hw1) {
  const int i = (blockIdx.x * 256 + threadIdx.x) * 4;
#pragma unroll
  for (int j = 0; j < 4; ++j) { ast32(hw0 + i + j, 0u); ast32(hw1 + i + j, 0u); }
}

// x -> bf16 copy (converting from fp32 if detected)
__global__ void k_convert(const void* __restrict__ xin, short* __restrict__ xbf,
                          const int* __restrict__ dflag) {
  const int f32 = *dflag;
  const size_t stride = (size_t)gridDim.x * 1024;
  size_t i = ((size_t)blockIdx.x * 256 + threadIdx.x) * 4;
  for (; i < (size_t)XELT; i += stride) {
    short4v v;
    if (f32) {
      const float4 f = *(const float4*)&((const float*)xin)[i];
      v[0] = f2bf(f.x); v[1] = f2bf(f.y); v[2] = f2bf(f.z); v[3] = f2bf(f.w);
    } else {
      v = *(const short4v*)&((const short*)xin)[i];
    }
    *(short4v*)&xbf[i] = v;
  }
}

// (R,C) -> (C,R) bf16 output, dtype-flagged input, 64x64 tiles
__global__ void k_transpose(const void* __restrict__ in, short* __restrict__ out,
                            int R, int C, const int* __restrict__ dflag) {
  __shared__ short tile[64][65];
  const int f32 = *dflag;
  const int r0 = blockIdx.x << 6, c0 = blockIdx.y << 6;
  const int tid = threadIdx.x;
#pragma unroll
  for (int it = 0; it < 8; ++it) {
    int idx = (it << 8) + tid;
    int r = idx >> 5, c2 = (idx & 31) << 1;
    if (f32) {
      const float* inF = (const float*)in;
      tile[r][c2]     = f2bf(inF[(size_t)(r0 + r) * C + c0 + c2]);
      tile[r][c2 + 1] = f2bf(inF[(size_t)(r0 + r) * C + c0 + c2 + 1]);
    } else {
      int v = *(const int*)&((const short*)in)[(size_t)(r0 + r) * C + c0 + c2];
      tile[r][c2]     = (short)(v & 0xffff);
      tile[r][c2 + 1] = (short)(((unsigned)v) >> 16);
    }
  }
  __syncthreads();
#pragma unroll
  for (int it = 0; it < 8; ++it) {
    int idx = (it << 8) + tid;
    int rr = idx >> 5, k2 = (idx & 31) << 1;
    unsigned int lo = (unsigned short)tile[k2][rr];
    unsigned int hi = (unsigned short)tile[k2 + 1][rr];
    *(unsigned int*)&out[(size_t)(c0 + rr) * R + r0 + k2] = lo | (hi << 16);
  }
}

// ---------------------------------------------------------------------------
// pi_chunk[r, 0:6144] = A[row(r), :] @ Bt^T, rows map the chunk's (b, t0+tt).
__launch_bounds__(256)
__global__ void k_gemm(const short* __restrict__ A, const short* __restrict__ Bt,
                       short* __restrict__ Cmat, int t0) {
  __shared__ short ldsA[128 * 64];
  __shared__ short ldsB[128 * 64];
  const int tid = threadIdx.x, lane = tid & 63, wv = tid >> 6;
  const int wm = wv >> 1, wn = wv & 1;
  const int r0 = blockIdx.x * 128;
  const size_t brow0 = (size_t)blockIdx.y * 128;
  f32x4 acc[4][4] = {};

  for (int kk = 0; kk < Hdim; kk += 64) {
#pragma unroll
    for (int p = 0; p < 4; ++p) {
      int slot = ((wv * 4 + p) << 6) + lane;
      int m = slot >> 3, gp = slot & 7;
      int gl = gp ^ (m & 7);
      int r = r0 + m;
      size_t arow = ((size_t)(r >> 6) * Tlen + t0 + (r & 63)) * Hdim;
      gld_lds16(A + arow + kk + (gl << 3), &ldsA[(wv * 4 + p) << 9]);
      gld_lds16(Bt + (brow0 + m) * Hdim + kk + (gl << 3), &ldsB[(wv * 4 + p) << 9]);
    }
    __syncthreads();
#pragma unroll
    for (int kh = 0; kh < 2; ++kh) {
      short8v af[4], bfv[4];
      const int gl = (kh << 2) + (lane >> 4);
#pragma unroll
      for (int mt = 0; mt < 4; ++mt) {
        int m = wm * 64 + mt * 16 + (lane & 15);
        af[mt] = *(const short8v*)&ldsA[m * 64 + ((gl ^ (m & 7)) << 3)];
      }
#pragma unroll
      for (int nt = 0; nt < 4; ++nt) {
        int n = wn * 64 + nt * 16 + (lane & 15);
        bfv[nt] = *(const short8v*)&ldsB[n * 64 + ((gl ^ (n & 7)) << 3)];
      }
#pragma unroll
      for (int mt = 0; mt < 4; ++mt)
#pragma unroll
        for (int nt = 0; nt < 4; ++nt)
          acc[mt][nt] = __builtin_amdgcn_mfma_f32_16x16x32_bf16(af[mt], bfv[nt], acc[mt][nt], 0, 0, 0);
    }
    __syncthreads();
  }
#pragma unroll
  for (int mt = 0; mt < 4; ++mt)
#pragma unroll
    for (int nt = 0; nt < 4; ++nt)
#pragma unroll
      for (int q = 0; q < 4; ++q) {
        size_t row = (size_t)r0 + wm * 64 + mt * 16 + ((lane >> 4) << 2) + q;
        size_t col = brow0 + wn * 64 + nt * 16 + (lane & 15);
        Cmat[row * NH6 + col] = f2bf(acc[mt][nt][q]);
      }
}

// ---------------------------------------------------------------------------
// Persistent recurrent scan, one TCH-step chunk. 256 WGs x 256 threads.
// WG (grp, gbid): batch rows grp*32..+31, hidden units gbid*8..+7.
// h ring: hw[4][64][1024] dwords, dword = (bf16 h << 16) | ((t+1) & 0xFFFF).
// Per step: 8 K-chunks polled in staggered order via depth-2 pipelined
// dwordx4 sc0sc1 loads with counted vmcnt; tags are the only sync.
__launch_bounds__(256, 1)
__global__ void k_scan(const short* __restrict__ pi, const short* __restrict__ WsT,
                       const void* __restrict__ bs, void* __restrict__ ybase, int yext,
                       void* __restrict__ outb, int fhoff, int fcoff,
                       unsigned int* hw, float* cbuf,
                       int t0, int isfirst,
                       const int* __restrict__ lengths, const int* __restrict__ dflag) {
  extern __shared__ short smem[];
  short* Wt = smem;                                   // 48*1032 shorts
  float* psred = (float*)(smem + 48 * 1032);          // 2 x 24*256 floats

  const int tid  = threadIdx.x, lane = tid & 63, wv = tid >> 6;
  const int bid  = blockIdx.x, grp = bid >> 7, gbid = bid & 127;
  const int rb0  = grp * 32;
  const int u0   = gbid * 8;
  const int f32io = *dflag;
  const int yf32  = yext & f32io;

  // --- one-time: weight slice to LDS (cols packed n = gate*8 + unit)
  for (int n = 0; n < 40; ++n) {
    const short* src = WsT + (size_t)((n >> 3) * Hdim + u0 + (n & 7)) * Hdim;
    *(short4v*)&Wt[n * 1032 + tid * 4] = *(const short4v*)&src[tid * 4];
  }
  short4v zz = {0, 0, 0, 0};
  for (int n = 40; n < 48; ++n) *(short4v*)&Wt[n * 1032 + tid * 4] = zz;

  const int grow = tid >> 3, gunit = tid & 7;
  const int gb = rb0 + grow;
  const int mylen = lengths[gb];
  const unsigned int selfoff = ((unsigned)gb << 10) | (unsigned)(u0 + gunit);

  float bias[5];
  int   psoff[5];
#pragma unroll
  for (int g = 0; g < 5; ++g) {
    bias[g] = f32io ? ((const float*)bs)[g * Hdim + u0 + gunit]
                    : bf2f(((const short*)bs)[g * Hdim + u0 + gunit]);
    int n = g * 8 + gunit, nt = n >> 4, cl = n & 15;
    int mt = grow >> 4, rw = grow & 15;
    int ln = ((rw >> 2) << 4) | cl, reg = rw & 3;
    psoff[g] = ((mt * 3 + nt) << 8) + (ln << 2) + reg;
  }

  // restore own state: h from ring slot (t0-1)&3 (zeros if first), c from cbuf
  float h_state = bf2f((short)(ald32(hw + (((unsigned)(t0 + 3) & 3) << 16) + selfoff) >> 16));
  float c_state = isfirst ? 0.0f : cbuf[(size_t)gb * Hdim + u0 + gunit];

  const int kb = wv << 8;                 // wave's K base (dword/unit index)
  const int klane = (lane >> 4) << 3;
  const int st = gbid & 7;                // chunk-order stagger

  for (int t = t0; t < t0 + TCH; ++t) {
    const unsigned int want = (unsigned)(t & 0xFFFF);
    // per-lane byte base: slot + row (rb0 + lane&15) + k(kb+klane)
    const char* pbb = (const char*)hw + (((size_t)((t + 3) & 3)) << 18)
                    + (((size_t)(rb0 + (lane & 15))) << 12)
                    + (((size_t)(kb + klane)) << 2);

    u32x4 A0, A1, A2, A3, B0, B1, B2, B3, E0, E1, E2, E3;
    f32x4 acc[2][3] = {};

    // prologue: 3 chunks in flight
    ZISSUE(A0, A1, A2, A3, st);
    ZISSUE(B0, B1, B2, B3, (st + 1) & 7);
    ZISSUE(E0, E1, E2, E3, (st + 2) & 7);

    // pi loads (6 dword loads; queue position after the 3 chunk issues --
    // accounted in the vmcnt numbers below)
    const short* pib = pi + (size_t)(gb * TCH + (t - t0)) * NH6 + u0 + gunit;
    float piv[6];
#pragma unroll
    for (int g = 0; g < 6; ++g) piv[g] = bf2f(pib[g << 10]);

    // Queue arithmetic (in-order vmcnt retirement): at block i's wait, the
    // loads younger than chunk i are: blocks 0-2: 2 chunks + pi6 = 14;
    // blocks 3-5: 2 chunks = 8; block 6: 1 chunk = 4; block 7: 0.
    PROC(A0, A1, A2, A3, st, 14);             ZISSUE(A0, A1, A2, A3, (st + 3) & 7);
    PROC(B0, B1, B2, B3, (st + 1) & 7, 14);   ZISSUE(B0, B1, B2, B3, (st + 4) & 7);
    PROC(E0, E1, E2, E3, (st + 2) & 7, 14);   ZISSUE(E0, E1, E2, E3, (st + 5) & 7);
    PROC(A0, A1, A2, A3, (st + 3) & 7, 8);    ZISSUE(A0, A1, A2, A3, (st + 6) & 7);
    PROC(B0, B1, B2, B3, (st + 4) & 7, 8);    ZISSUE(B0, B1, B2, B3, (st + 7) & 7);
    PROC(E0, E1, E2, E3, (st + 5) & 7, 8);
    PROC(A0, A1, A2, A3, (st + 6) & 7, 4);
    PROC(B0, B1, B2, B3, (st + 7) & 7, 0);

    // psred double-buffered by (t&1): single barrier per step.
    float* ps_w = psred + ((t & 1) * 6144);
#pragma unroll
    for (int mt = 0; mt < 2; ++mt)
#pragma unroll
      for (int nt = 0; nt < 3; ++nt)
        *(f32x4*)&ps_w[((wv * 6 + mt * 3 + nt) << 8) + (lane << 2)] = acc[mt][nt];
    __syncthreads();

    float ps[5];
#pragma unroll
    for (int g = 0; g < 5; ++g) {
      int o = psoff[g];
      ps[g] = bias[g] + ps_w[o] + ps_w[1536 + o] + ps_w[3072 + o] + ps_w[4608 + o];
    }
    float ig = sigm(piv[0] + ps[0]);
    float fg = sigm(piv[1] + ps[1]);
    float mg = tanh_(piv[2] + ps[2]);
    float og = sigm(piv[3] + ps[3]);
    float hw_g = sigm(piv[4] + ps[4]);
    float cn  = ig * mg + fg * c_state;
    float outv = og * tanh_(cn);
    outv = hw_g * outv + (1.0f - hw_g) * piv[5];
    const bool valid = (t < mylen);
    if (valid) { c_state = cn; h_state = outv; }

    // publish h(t) tagged t+1 into ring slot t&3 first, then the y-store
    unsigned int pk = (((unsigned)(unsigned short)f2bf(h_state)) << 16) |
                      ((unsigned)((t + 1) & 0xFFFF));
    ast32(hw + (((unsigned)t & 3) << 16) + selfoff, pk);

    size_t yi = ((size_t)gb * Tlen + t) * Hdim + u0 + gunit;
    if (yf32) ((float*)ybase)[yi] = valid ? outv : 0.0f;
    else      ((short*)ybase)[yi] = valid ? f2bf(outv) : (short)0;
  }

  cbuf[(size_t)gb * Hdim + u0 + gunit] = c_state;
  const size_t sidx = (size_t)gb * Hdim + u0 + gunit;
  if (f32io) {
    ((float*)outb)[fhoff + sidx] = h_state;
    ((float*)outb)[fcoff + sidx] = c_state;
  } else {
    ((short*)outb)[fhoff + sidx] = f2bf(h_state);
    ((short*)outb)[fcoff + sidx] = f2bf(c_state);
  }
}

// ---------------------------------------------------------------------------
extern "C" void kernel_launch(void* const* d_in, const int* in_sizes, int n_in,
                              void* d_out, int out_size, void* d_ws, size_t ws_size,
                              hipStream_t stream) {
  const void* x       = d_in[0];
  const int*  lengths = (const int*)d_in[1];
  const void* Wi0     = d_in[2];
  const void* Ws0     = d_in[3];
  const void* bs0     = d_in[4];
  const void* Wi1     = d_in[5];
  const void* Ws1     = d_in[6];
  const void* bs1     = d_in[7];
  char* ws = (char*)d_ws;

  short* xbf   = (short*)(ws + WS_XBF);
  short* y0    = (short*)(ws + WS_Y0);
  short* WiT0  = (short*)(ws + WS_WIT0);
  short* WiT1  = (short*)(ws + WS_WIT1);
  short* WsT0  = (short*)(ws + WS_WST0);
  short* WsT1  = (short*)(ws + WS_WST1);
  short* pibuf = (short*)(ws + WS_PI);
  unsigned int* hw0 = (unsigned int*)(ws + WS_HW0);
  unsigned int* hw1 = (unsigned int*)(ws + WS_HW1);
  float* cbuf  = (float*)(ws + WS_CB);
  int*   dflag = (int*)(ws + WS_DFLAG);

  k_detect<<<1, 256, 0, stream>>>((const short*)x, dflag);
  k_init<<<256, 256, 0, stream>>>(hw0, hw1);
  k_convert<<<2048, 256, 0, stream>>>(x, xbf, dflag);
  k_transpose<<<dim3(16, 96), 256, 0, stream>>>(Wi0, WiT0, 1024, NH6, dflag);
  k_transpose<<<dim3(16, 80), 256, 0, stream>>>(Ws0, WsT0, 1024, NH5, dflag);
  k_transpose<<<dim3(16, 96), 256, 0, stream>>>(Wi1, WiT1, 1024, NH6, dflag);
  k_transpose<<<dim3(16, 80), 256, 0, stream>>>(Ws1, WsT1, 1024, NH5, dflag);

  const unsigned int scan_lds = 48 * 1032 * 2 + 2 * 24 * 256 * 4;  // 148,224 B
  hipFuncSetAttribute((const void*)k_scan, hipFuncAttributeMaxDynamicSharedMemorySize,
                      (int)scan_lds);

  for (int layer = 0; layer < 2; ++layer) {
    const short* Asrc = (layer == 0) ? xbf : y0;
    const short* WiT  = (layer == 0) ? WiT0 : WiT1;
    const short* WsT  = (layer == 0) ? WsT0 : WsT1;
    const void*  bsp  = (layer == 0) ? bs0 : bs1;
    unsigned int* hwp = (layer == 0) ? hw0 : hw1;
    for (int c = 0; c < NCH; ++c) {
      k_gemm<<<dim3(32, 48), 256, 0, stream>>>(Asrc, WiT, pibuf, c * TCH);

      const short* pi_p = pibuf; const short* ws_p = WsT; const void* bs_p = bsp;
      void* y_p  = (layer == 0) ? (void*)y0 : d_out;
      int yext   = (layer == 0) ? 0 : 1;
      void* outp = d_out;
      int fh = OUT_FH + layer * 65536, fcv = OUT_FC + layer * 65536;
      unsigned int* hwq = hwp; float* cb = cbuf;
      int tt0 = c * TCH;
      int isf = (c == 0) ? 1 : 0;
      const int* len = lengths; const int* df = dflag;
      void* args[14] = {&pi_p, &ws_p, &bs_p, &y_p, &yext, &outp, &fh, &fcv,
                        &hwq, &cb, &tt0, &isf, &len, &df};
      hipLaunchCooperativeKernel((void*)k_scan, dim3(256), dim3(256), args,
                                 scan_lds, stream);
    }
  }
}